// Round 4
// baseline (1205.127 us; speedup 1.0000x reference)
//
#include <hip/hip_runtime.h>
#include <cstdint>
#include <cstddef>

typedef unsigned short u16;
typedef __attribute__((ext_vector_type(8))) short short8;
typedef __attribute__((ext_vector_type(8))) u16 ushort8;
typedef __attribute__((ext_vector_type(4))) float float4_t;

#define BB 8
#define NN 8192
#define DD 64
#define NTILES 64            // 8192 / 128 column tiles
#define TILE_SHORTS 8192     // 128 points * 64 k (bf16)

__device__ inline u16 f32_to_bf16(float f) {
  unsigned u = __float_as_uint(f);
  u += 0x7FFFu + ((u >> 16) & 1u);   // RNE
  return (u16)(u >> 16);
}

__device__ inline unsigned enc_ord(float f) {
  unsigned u = __float_as_uint(f);
  return (u & 0x80000000u) ? ~u : (u | 0x80000000u);
}
__device__ inline float dec_ord(unsigned u) {
  return __uint_as_float((u & 0x80000000u) ? (u & 0x7fffffffu) : ~u);
}

// ---------------------------------------------------------------------------
// K1: fp32 -> bf16 pre-swizzle + 0.5*|v|^2.  Coalesced-store version:
// each wave owns a 16x32 sub-block (one chunk pair) and writes a contiguous
// 2KB run; the s2 phase re-reads the same rows (L1-hot).
// Chunk layout per 128x64 tile: [I(8)][s(2)] chunks of 1KB; within a chunk
// lane l (l=qq*16+rl) holds point I*16+rl, k = s*32+qq*8+j (j=0..7, 16B).
// Fallback path: also zeroes the atomic max buffers.
// ---------------------------------------------------------------------------
__global__ __launch_bounds__(256) void pre_kernel(
    const float* __restrict__ x, const float* __restrict__ y,
    u16* __restrict__ xs, u16* __restrict__ ys,
    float* __restrict__ x2h, float* __restrict__ y2h,
    unsigned* __restrict__ rowmax_u, unsigned* __restrict__ colmax_u,
    const int use_part)
{
  const int bid = blockIdx.x;          // 2048: 0..1023 -> x, 1024..2047 -> y
  const int tid = threadIdx.x;

  if (!use_part) {
    if (bid < 256)                     colmax_u[(bid << 8) | tid] = 0u;
    else if (bid < 512)                rowmax_u[((bid - 256) << 8) | tid] = 0u;
  }

  const bool isY = bid >= 1024;
  const float* src = isY ? y : x;
  u16* dst = isY ? ys : xs;
  float* s2 = isY ? y2h : x2h;

  const int base = (bid & 1023) << 6;  // first of 64 global rows (b*8192+n)

  // ---- phase A: swizzle, coalesced stores ----
  {
    const int w = tid >> 6, lane = tid & 63;
    const int qq = lane >> 4, rl = lane & 15;
    const int grow = base + w*16 + rl;          // global row
    const int b  = grow >> 13;
    const int n  = grow & (NN - 1);
    const int nt = n >> 7;
    const int I  = (n >> 4) & 7;
    u16* tb = dst + (size_t)((b << 6) | nt) * TILE_SHORTS;
#pragma unroll
    for (int s = 0; s < 2; ++s) {
      const float4* rp = (const float4*)(src + (size_t)grow * DD + s*32 + qq*8);
      float4 f0 = rp[0], f1 = rp[1];
      ushort8 o;
      o[0] = f32_to_bf16(f0.x); o[1] = f32_to_bf16(f0.y);
      o[2] = f32_to_bf16(f0.z); o[3] = f32_to_bf16(f0.w);
      o[4] = f32_to_bf16(f1.x); o[5] = f32_to_bf16(f1.y);
      o[6] = f32_to_bf16(f1.z); o[7] = f32_to_bf16(f1.w);
      *(ushort8*)(tb + (I*2 + s)*512 + lane*8) = o;   // contiguous 1KB/wave
    }
  }

  // ---- phase B: 0.5*|row|^2 (4 threads/row, L1-hot reads) ----
  {
    const int row = base | (tid >> 2);
    const int kq  = tid & 3;
    const float4* rp = (const float4*)(src + (size_t)row * DD + kq * 16);
    float ss = 0.f;
#pragma unroll
    for (int k = 0; k < 4; ++k) {
      float4 f = rp[k];
      ss += f.x*f.x + f.y*f.y + f.z*f.z + f.w*f.w;
    }
    ss += __shfl_xor(ss, 1);
    ss += __shfl_xor(ss, 2);
    if (kq == 0) s2[row] = 0.5f * ss;
  }
}

// ---------------------------------------------------------------------------
// K2: main. Barrier-free K-loop, 4 blocks/CU. Block = 4 waves; each wave owns
// 128 rows x 32 cols of each col-tile; sweeps its half of the 64 col-tiles.
// B fragments loaded straight from L2-resident ys with 1-iter reg prefetch.
// acc = xy - x2/2 via fp32 C-init. Grid 1024 = 8 b (XCD-affine) x 64 nt x 2 h.
// ---------------------------------------------------------------------------
__global__ __launch_bounds__(256, 4) void main_kernel(
    const u16* __restrict__ xs, const u16* __restrict__ ys,
    const float* __restrict__ x2h, const float* __restrict__ y2h,
    float* __restrict__ rowpart, float* __restrict__ colpart,
    unsigned* __restrict__ rowmax_u, unsigned* __restrict__ colmax_u,
    const int use_part)
{
  __shared__ float rowbuf[4][128];

  const int bid = blockIdx.x;            // 1024
  const int b   = bid & 7;               // XCD-affine
  const int nt  = (bid >> 3) & 63;
  const int h   = bid >> 9;              // 0..1
  const int mt_start = h << 5, mt_end = mt_start + 32;
  const int tid = threadIdx.x;
  const int w = tid >> 6, lane = tid & 63;   // w = column-slice owner
  const int l15 = lane & 15, q = lane >> 4;
  const int n0 = nt << 7;

  // ---- A fragments: all 128 rows, both K-halves, pinned in registers ----
  const u16* xs_tile = xs + (size_t)((b << 6) | nt) * TILE_SHORTS;
  short8 afr[8][2];
#pragma unroll
  for (int i = 0; i < 8; ++i)
#pragma unroll
    for (int s = 0; s < 2; ++s)
      afr[i][s] = *(const short8*)(xs_tile + (i*2 + s)*512 + lane*8);

  // ---- C-init quads: -x2/2 per row (fp32 exact) ----
  float4_t negx2[8];
  const float* x2b = x2h + b*NN + n0;
#pragma unroll
  for (int i = 0; i < 8; ++i) {
    float4_t v = *(const float4_t*)(x2b + i*16 + q*4);
    negx2[i] = {-v[0], -v[1], -v[2], -v[3]};
  }

  float rowmax[8][4];
#pragma unroll
  for (int i = 0; i < 8; ++i)
#pragma unroll
    for (int r = 0; r < 4; ++r) rowmax[i][r] = -3.0e38f;

  const float* y2b = y2h + b*NN;
  const u16* ys_b  = ys + (size_t)(b << 6) * TILE_SHORTS;
  float* colp      = colpart + (size_t)((b << 6) | nt) * NN;
  unsigned* colu   = colmax_u + b*NN;

  // ---- register prefetch for mt_start ----
  short8 bcur[2][2];
  float y2cur[2];
  {
    const u16* g = ys_b + (size_t)mt_start * TILE_SHORTS;
#pragma unroll
    for (int j = 0; j < 2; ++j) {
#pragma unroll
      for (int s = 0; s < 2; ++s)
        bcur[j][s] = *(const short8*)(g + ((2*w + j)*2 + s)*512 + lane*8);
      y2cur[j] = y2b[mt_start*128 + w*32 + j*16 + l15];
    }
  }

  for (int mt = mt_start; mt < mt_end; ++mt) {
    // prefetch mt+1 (clamped)
    const int mtn = (mt + 1 < mt_end) ? (mt + 1) : mt_start;
    short8 bnext[2][2];
    float y2next[2];
    const u16* g = ys_b + (size_t)mtn * TILE_SHORTS;
#pragma unroll
    for (int j = 0; j < 2; ++j) {
#pragma unroll
      for (int s = 0; s < 2; ++s)
        bnext[j][s] = *(const short8*)(g + ((2*w + j)*2 + s)*512 + lane*8);
      y2next[j] = y2b[mtn*128 + w*32 + j*16 + l15];
    }

    float cmax[2];
#pragma unroll
    for (int j = 0; j < 2; ++j) {
      // acc = xy - x2/2 (C carries exact fp32 -x2/2); j-sequential keeps
      // live accumulators at 8 x float4 -> VGPR <= 128 (4 waves/SIMD)
      float4_t acc[8];
#pragma unroll
      for (int i = 0; i < 8; ++i)
        acc[i] = __builtin_amdgcn_mfma_f32_16x16x32_bf16(afr[i][0], bcur[j][0], negx2[i], 0, 0, 0);
#pragma unroll
      for (int i = 0; i < 8; ++i)
        acc[i] = __builtin_amdgcn_mfma_f32_16x16x32_bf16(afr[i][1], bcur[j][1], acc[i], 0, 0, 0);

      // col side: pure max over rows in-lane
      float m01 = fmaxf(fmaxf(acc[0][0], acc[0][1]), fmaxf(acc[0][2], acc[0][3]));
#pragma unroll
      for (int i = 1; i < 8; ++i) {
        float mi = fmaxf(fmaxf(acc[i][0], acc[i][1]), fmaxf(acc[i][2], acc[i][3]));
        m01 = fmaxf(m01, mi);
      }
      cmax[j] = m01;

      // row side: rowmax = max(acc - y2/2) = -min(d^2)/2
      const float y2j = y2cur[j];
#pragma unroll
      for (int i = 0; i < 8; ++i)
#pragma unroll
        for (int r = 0; r < 4; ++r)
          rowmax[i][r] = fmaxf(rowmax[i][r], acc[i][r] - y2j);
    }

    // col-max: combine q-groups (rows) via shuffles; wave-private, no barrier
#pragma unroll
    for (int j = 0; j < 2; ++j) {
      cmax[j] = fmaxf(cmax[j], __shfl_xor(cmax[j], 16));
      cmax[j] = fmaxf(cmax[j], __shfl_xor(cmax[j], 32));
    }
    float cv = (q & 1) ? cmax[1] : cmax[0];
    const int m = (mt << 7) + w*32 + q*16 + l15;   // valid for q<2
    if (q < 2) {
      if (use_part) colp[m] = cv;
      else          atomicMax(&colu[m], enc_ord(cv));
    }

#pragma unroll
    for (int j = 0; j < 2; ++j) {
#pragma unroll
      for (int s = 0; s < 2; ++s) bcur[j][s] = bnext[j][s];
      y2cur[j] = y2next[j];
    }
  }

  // ---- row side finalize: shfl over cols (l15), then 4-wave LDS combine ----
#pragma unroll
  for (int i = 0; i < 8; ++i)
#pragma unroll
    for (int r = 0; r < 4; ++r) {
      float v = rowmax[i][r];
      v = fmaxf(v, __shfl_xor(v, 1));
      v = fmaxf(v, __shfl_xor(v, 2));
      v = fmaxf(v, __shfl_xor(v, 4));
      v = fmaxf(v, __shfl_xor(v, 8));
      rowmax[i][r] = v;
    }
  if (l15 == 0) {
#pragma unroll
    for (int i = 0; i < 8; ++i)
#pragma unroll
      for (int r = 0; r < 4; ++r)
        rowbuf[w][i*16 + q*4 + r] = rowmax[i][r];
  }
  __syncthreads();
  if (tid < 128) {
    float v = fmaxf(fmaxf(rowbuf[0][tid], rowbuf[1][tid]),
                    fmaxf(rowbuf[2][tid], rowbuf[3][tid]));   // -min(d^2)/2
    if (use_part) rowpart[(size_t)((h << 9) | (b << 6) | nt) * 128 + tid] = v;
    else          atomicMax(&rowmax_u[b*NN + n0 + tid], enc_ord(v));
  }
}

// ---------------------------------------------------------------------------
// K3: col combine over 64 nt + sqrt; row combine over 2 h + sqrt; block sums.
// ---------------------------------------------------------------------------
__global__ __launch_bounds__(256) void reduce_kernel(
    const float* __restrict__ rowpart, const float* __restrict__ colpart,
    const unsigned* __restrict__ rowmax_u, const unsigned* __restrict__ colmax_u,
    const float* __restrict__ y2h,
    float* __restrict__ partials, const int use_part)
{
  const int bid = blockIdx.x;          // 256
  const int tid = threadIdx.x;
  const int g = bid*256 + tid;         // 0..65535
  const int b = g >> 13, m = g & (NN - 1);

  float vc, vr;
  if (use_part) {
    vc = -3.0e38f;
#pragma unroll 8
    for (int nt = 0; nt < 64; ++nt)
      vc = fmaxf(vc, colpart[(size_t)((b << 6) | nt) * NN + m]);
    const int nt = m >> 7, r = m & 127;
    float r0 = rowpart[(size_t)((0 << 9) | (b << 6) | nt) * 128 + r];
    float r1 = rowpart[(size_t)((1 << 9) | (b << 6) | nt) * 128 + r];
    vr = fmaxf(r0, r1);
  } else {
    vc = dec_ord(colmax_u[g]);
    vr = dec_ord(rowmax_u[g]);
  }
  float s = sqrtf(fmaxf(2.f*(y2h[g] - vc), 0.f))   // nearest-x for this y
          + sqrtf(fmaxf(-2.f*vr, 0.f));            // nearest-y for this x

#pragma unroll
  for (int d = 1; d < 64; d <<= 1) s += __shfl_xor(s, d);
  __shared__ float wsum[4];
  if ((tid & 63) == 0) wsum[tid >> 6] = s;
  __syncthreads();
  if (tid == 0) partials[bid] = wsum[0] + wsum[1] + wsum[2] + wsum[3];
}

// ---------------------------------------------------------------------------
// K4: final scalar
// ---------------------------------------------------------------------------
__global__ void final_kernel(const float* __restrict__ partials, float* __restrict__ out) {
  const int tid = threadIdx.x;         // 256
  float s = partials[tid];
#pragma unroll
  for (int d = 1; d < 64; d <<= 1) s += __shfl_xor(s, d);
  __shared__ float wsum[4];
  if ((tid & 63) == 0) wsum[tid >> 6] = s;
  __syncthreads();
  if (tid == 0) out[0] = (wsum[0] + wsum[1] + wsum[2] + wsum[3]) * (1.0f / 65536.0f);
}

// ---------------------------------------------------------------------------
extern "C" void kernel_launch(void* const* d_in, const int* in_sizes, int n_in,
                              void* d_out, int out_size, void* d_ws, size_t ws_size,
                              hipStream_t stream) {
  const float* x = (const float*)d_in[0];
  const float* y = (const float*)d_in[1];
  float* out = (float*)d_out;

  char* p = (char*)d_ws;
  u16* xs = (u16*)p;            p += (size_t)512 * 16384;   // 8 MiB
  u16* ys = (u16*)p;            p += (size_t)512 * 16384;   // 8 MiB
  float* x2h = (float*)p;       p += (size_t)65536 * 4;
  float* y2h = (float*)p;       p += (size_t)65536 * 4;
  float* partials = (float*)p;  p += 4096;
  char* tail = p;
  // partial path: colpart 16 MiB + rowpart 512 KiB
  float* colpart = (float*)tail;
  float* rowpart = (float*)(tail + (size_t)512 * 8192 * 4);
  // atomic fallback: two 256 KiB ordered-uint max buffers
  unsigned* colmax_u = (unsigned*)tail;
  unsigned* rowmax_u = (unsigned*)(tail + (size_t)65536 * 4);
  const size_t need_part = (size_t)(tail - (char*)d_ws) +
                           (size_t)512 * 8192 * 4 + (size_t)1024 * 128 * 4;
  const int use_part = (ws_size >= need_part) ? 1 : 0;

  pre_kernel<<<dim3(2048), dim3(256), 0, stream>>>(x, y, xs, ys, x2h, y2h,
                                                   rowmax_u, colmax_u, use_part);
  main_kernel<<<dim3(1024), dim3(256), 0, stream>>>(xs, ys, x2h, y2h,
                                                    rowpart, colpart,
                                                    rowmax_u, colmax_u, use_part);
  reduce_kernel<<<dim3(256), dim3(256), 0, stream>>>(rowpart, colpart,
                                                     rowmax_u, colmax_u, y2h,
                                                     partials, use_part);
  final_kernel<<<dim3(1), dim3(256), 0, stream>>>(partials, out);
}

// Round 5
// 240.361 us; speedup vs baseline: 5.0138x; 5.0138x over previous
//
#include <hip/hip_runtime.h>
#include <cstdint>
#include <cstddef>

typedef unsigned short u16;
typedef __attribute__((ext_vector_type(8))) short short8;
typedef __attribute__((ext_vector_type(8))) u16 ushort8;
typedef __attribute__((ext_vector_type(4))) float float4_t;

#define BB 8
#define NN 8192
#define DD 64
#define NTILES 64            // 8192 / 128 column tiles
#define TILE_SHORTS 8192     // 128 points * 64 k (bf16)

__device__ inline u16 f32_to_bf16(float f) {
  unsigned u = __float_as_uint(f);
  u += 0x7FFFu + ((u >> 16) & 1u);   // RNE
  return (u16)(u >> 16);
}

__device__ inline unsigned enc_ord(float f) {
  unsigned u = __float_as_uint(f);
  return (u & 0x80000000u) ? ~u : (u | 0x80000000u);
}
__device__ inline float dec_ord(unsigned u) {
  return __uint_as_float((u & 0x80000000u) ? (u & 0x7fffffffu) : ~u);
}

// ---------------------------------------------------------------------------
// K1: fp32 -> bf16 pre-swizzle + 0.5*|v|^2 (coalesced stores); also zeroes
// the ordered-uint col-max buffer and the scalar output.
// Chunk layout per 128x64 tile: [I(8)][s(2)] chunks of 1KB; within a chunk
// lane l (l=qq*16+rl) holds point I*16+rl, k = s*32+qq*8+j (j=0..7, 16B).
// ---------------------------------------------------------------------------
__global__ __launch_bounds__(256) void pre_kernel(
    const float* __restrict__ x, const float* __restrict__ y,
    u16* __restrict__ xs, u16* __restrict__ ys,
    float* __restrict__ x2h, float* __restrict__ y2h,
    unsigned* __restrict__ colmax_u, float* __restrict__ out)
{
  const int bid = blockIdx.x;          // 2048: 0..1023 -> x, 1024..2047 -> y
  const int tid = threadIdx.x;

  if (bid < 256) colmax_u[(bid << 8) | tid] = 0u;   // enc_ord floor
  if (bid == 0 && tid == 0) out[0] = 0.f;

  const bool isY = bid >= 1024;
  const float* src = isY ? y : x;
  u16* dst = isY ? ys : xs;
  float* s2 = isY ? y2h : x2h;

  const int base = (bid & 1023) << 6;  // first of 64 global rows (b*8192+n)

  // ---- phase A: swizzle, coalesced 1KB/wave stores ----
  {
    const int w = tid >> 6, lane = tid & 63;
    const int qq = lane >> 4, rl = lane & 15;
    const int grow = base + w*16 + rl;          // global row
    const int b  = grow >> 13;
    const int n  = grow & (NN - 1);
    const int nt = n >> 7;
    const int I  = (n >> 4) & 7;
    u16* tb = dst + (size_t)((b << 6) | nt) * TILE_SHORTS;
#pragma unroll
    for (int s = 0; s < 2; ++s) {
      const float4* rp = (const float4*)(src + (size_t)grow * DD + s*32 + qq*8);
      float4 f0 = rp[0], f1 = rp[1];
      ushort8 o;
      o[0] = f32_to_bf16(f0.x); o[1] = f32_to_bf16(f0.y);
      o[2] = f32_to_bf16(f0.z); o[3] = f32_to_bf16(f0.w);
      o[4] = f32_to_bf16(f1.x); o[5] = f32_to_bf16(f1.y);
      o[6] = f32_to_bf16(f1.z); o[7] = f32_to_bf16(f1.w);
      *(ushort8*)(tb + (I*2 + s)*512 + lane*8) = o;
    }
  }

  // ---- phase B: 0.5*|row|^2 (4 threads/row, L1-hot reads) ----
  {
    const int row = base | (tid >> 2);
    const int kq  = tid & 3;
    const float4* rp = (const float4*)(src + (size_t)row * DD + kq * 16);
    float ss = 0.f;
#pragma unroll
    for (int k = 0; k < 4; ++k) {
      float4 f = rp[k];
      ss += f.x*f.x + f.y*f.y + f.z*f.z + f.w*f.w;
    }
    ss += __shfl_xor(ss, 1);
    ss += __shfl_xor(ss, 2);
    if (kq == 0) s2[row] = 0.5f * ss;
  }
}

// ---------------------------------------------------------------------------
// K2: main. Barrier-free, software-pipelined K-loop (acc double-buffer at
// j-granularity: epilogue of stage k overlaps MFMA issue of stage k+1).
// Block = 4 waves; each wave owns 128 rows x 32 cols; 2 blocks/CU.
// acc = xy - x2/2 via fp32 C-init. Col-max via device atomicMax (ordered
// uint); row-max in registers. Grid 512 = 8 b (XCD-affine) x 64 nt.
// ---------------------------------------------------------------------------
__global__ __launch_bounds__(256, 2) void main_kernel(
    const u16* __restrict__ xs, const u16* __restrict__ ys,
    const float* __restrict__ x2h, const float* __restrict__ y2h,
    float* __restrict__ a_min, unsigned* __restrict__ colmax_u)
{
  __shared__ float rowbuf[4][128];

  const int bid = blockIdx.x;            // 512
  const int b   = bid & 7;               // XCD-affine
  const int nt  = bid >> 3;
  const int tid = threadIdx.x;
  const int w = tid >> 6, lane = tid & 63;   // w = column-slice owner
  const int l15 = lane & 15, q = lane >> 4;
  const int n0 = nt << 7;

  // ---- A fragments: all 128 rows, both K-halves, pinned in registers ----
  const u16* xs_tile = xs + (size_t)((b << 6) | nt) * TILE_SHORTS;
  short8 afr[8][2];
#pragma unroll
  for (int i = 0; i < 8; ++i)
#pragma unroll
    for (int s = 0; s < 2; ++s)
      afr[i][s] = *(const short8*)(xs_tile + (i*2 + s)*512 + lane*8);

  // ---- C-init quads: -x2/2 per row (fp32 exact) ----
  float4_t negx2[8];
  const float* x2b = x2h + b*NN + n0;
#pragma unroll
  for (int i = 0; i < 8; ++i) {
    float4_t v = *(const float4_t*)(x2b + i*16 + q*4);
    negx2[i] = {-v[0], -v[1], -v[2], -v[3]};
  }

  float rowmax[8][4];
#pragma unroll
  for (int i = 0; i < 8; ++i)
#pragma unroll
    for (int r = 0; r < 4; ++r) rowmax[i][r] = -3.0e38f;

  const float* y2b = y2h + b*NN;
  const u16* ys_b  = ys + (size_t)(b << 6) * TILE_SHORTS;
  unsigned* colu   = colmax_u + b*NN;

#define MFMA_STAGE(ACC, B0, B1)                                                \
  do {                                                                         \
    _Pragma("unroll") for (int i = 0; i < 8; ++i)                              \
      ACC[i] = __builtin_amdgcn_mfma_f32_16x16x32_bf16(afr[i][0], B0, negx2[i], 0, 0, 0); \
    _Pragma("unroll") for (int i = 0; i < 8; ++i)                              \
      ACC[i] = __builtin_amdgcn_mfma_f32_16x16x32_bf16(afr[i][1], B1, ACC[i], 0, 0, 0);   \
  } while (0)

#define EPI(ACC, Y2V, MBASE)                                                   \
  do {                                                                         \
    float cm = fmaxf(fmaxf(ACC[0][0], ACC[0][1]), fmaxf(ACC[0][2], ACC[0][3]));\
    _Pragma("unroll") for (int i = 1; i < 8; ++i) {                            \
      float mi = fmaxf(fmaxf(ACC[i][0], ACC[i][1]), fmaxf(ACC[i][2], ACC[i][3]));\
      cm = fmaxf(cm, mi);                                                      \
    }                                                                          \
    cm = fmaxf(cm, __shfl_xor(cm, 16));                                        \
    cm = fmaxf(cm, __shfl_xor(cm, 32));                                        \
    if (q == 0) atomicMax(&colu[(MBASE) + l15], enc_ord(cm));                  \
    _Pragma("unroll") for (int i = 0; i < 8; ++i)                              \
      _Pragma("unroll") for (int r = 0; r < 4; ++r)                            \
        rowmax[i][r] = fmaxf(rowmax[i][r], ACC[i][r] - (Y2V));                 \
  } while (0)

  // ---- prologue: tile 0 fragments + first MFMA stage (j=0) ----
  short8 bcur0[2], bcur1[2], bnx0[2], bnx1[2];
  float y2c0, y2c1;
  {
    const u16* g = ys_b;
    bcur0[0] = *(const short8*)(g + ((2*w + 0)*2 + 0)*512 + lane*8);
    bcur0[1] = *(const short8*)(g + ((2*w + 0)*2 + 1)*512 + lane*8);
    bcur1[0] = *(const short8*)(g + ((2*w + 1)*2 + 0)*512 + lane*8);
    bcur1[1] = *(const short8*)(g + ((2*w + 1)*2 + 1)*512 + lane*8);
    y2c0 = y2b[w*32 + l15];
    y2c1 = y2b[w*32 + 16 + l15];
  }
  float4_t accA[8], accB[8];
  MFMA_STAGE(accA, bcur0[0], bcur0[1]);
  float y2A = y2c0;

  for (int mt = 0; mt < NTILES - 1; ++mt) {
    // prefetch tile mt+1
    const u16* g = ys_b + (size_t)(mt + 1) * TILE_SHORTS;
    bnx0[0] = *(const short8*)(g + ((2*w + 0)*2 + 0)*512 + lane*8);
    bnx0[1] = *(const short8*)(g + ((2*w + 0)*2 + 1)*512 + lane*8);
    bnx1[0] = *(const short8*)(g + ((2*w + 1)*2 + 0)*512 + lane*8);
    bnx1[1] = *(const short8*)(g + ((2*w + 1)*2 + 1)*512 + lane*8);
    float y2n0 = y2b[(mt + 1)*128 + w*32 + l15];
    float y2n1 = y2b[(mt + 1)*128 + w*32 + 16 + l15];

    // stage (mt, j1): MFMA into accB, then epilogue of accA (ready long ago)
    MFMA_STAGE(accB, bcur1[0], bcur1[1]);
    EPI(accA, y2A, (mt << 7) + w*32);

    // rotate to tile mt+1 (waits vmcnt for the prefetch)
    bcur0[0] = bnx0[0]; bcur0[1] = bnx0[1];
    bcur1[0] = bnx1[0]; bcur1[1] = bnx1[1];
    const float y2Bv = y2c1;
    y2c0 = y2n0; y2c1 = y2n1;

    // stage (mt+1, j0): MFMA into accA, then epilogue of accB
    MFMA_STAGE(accA, bcur0[0], bcur0[1]);
    y2A = y2c0;
    EPI(accB, y2Bv, (mt << 7) + w*32 + 16);
  }
  // tail: tile 63 j1 + both epilogues
  MFMA_STAGE(accB, bcur1[0], bcur1[1]);
  EPI(accA, y2A, ((NTILES - 1) << 7) + w*32);
  EPI(accB, y2c1, ((NTILES - 1) << 7) + w*32 + 16);

#undef MFMA_STAGE
#undef EPI

  // ---- row side finalize: shfl over cols (l15), then 4-wave LDS combine ----
#pragma unroll
  for (int i = 0; i < 8; ++i)
#pragma unroll
    for (int r = 0; r < 4; ++r) {
      float v = rowmax[i][r];
      v = fmaxf(v, __shfl_xor(v, 1));
      v = fmaxf(v, __shfl_xor(v, 2));
      v = fmaxf(v, __shfl_xor(v, 4));
      v = fmaxf(v, __shfl_xor(v, 8));
      rowmax[i][r] = v;
    }
  if (l15 == 0) {
#pragma unroll
    for (int i = 0; i < 8; ++i)
#pragma unroll
      for (int r = 0; r < 4; ++r)
        rowbuf[w][i*16 + q*4 + r] = rowmax[i][r];
  }
  __syncthreads();
  if (tid < 128) {
    float v = fmaxf(fmaxf(rowbuf[0][tid], rowbuf[1][tid]),
                    fmaxf(rowbuf[2][tid], rowbuf[3][tid]));   // -min(d^2)/2
    a_min[b*NN + n0 + tid] = sqrtf(fmaxf(-2.f * v, 0.f));
  }
}

// ---------------------------------------------------------------------------
// K3: per-element col sqrt + add a_min; block sum; atomicAdd scaled result.
// ---------------------------------------------------------------------------
__global__ __launch_bounds__(256) void reduce_kernel(
    const unsigned* __restrict__ colmax_u, const float* __restrict__ y2h,
    const float* __restrict__ a_min, float* __restrict__ out)
{
  const int bid = blockIdx.x;          // 256
  const int tid = threadIdx.x;
  const int g = bid*256 + tid;         // 0..65535

  float vc = dec_ord(colmax_u[g]);
  float s = sqrtf(fmaxf(2.f*(y2h[g] - vc), 0.f))   // nearest-x for this y
          + a_min[g];                              // nearest-y for this x

#pragma unroll
  for (int d = 1; d < 64; d <<= 1) s += __shfl_xor(s, d);
  __shared__ float wsum[4];
  if ((tid & 63) == 0) wsum[tid >> 6] = s;
  __syncthreads();
  if (tid == 0)
    atomicAdd(out, (wsum[0] + wsum[1] + wsum[2] + wsum[3]) * (1.0f / 65536.0f));
}

// ---------------------------------------------------------------------------
extern "C" void kernel_launch(void* const* d_in, const int* in_sizes, int n_in,
                              void* d_out, int out_size, void* d_ws, size_t ws_size,
                              hipStream_t stream) {
  const float* x = (const float*)d_in[0];
  const float* y = (const float*)d_in[1];
  float* out = (float*)d_out;

  char* p = (char*)d_ws;
  u16* xs = (u16*)p;            p += (size_t)512 * 16384;   // 8 MiB
  u16* ys = (u16*)p;            p += (size_t)512 * 16384;   // 8 MiB
  float* x2h = (float*)p;       p += (size_t)65536 * 4;
  float* y2h = (float*)p;       p += (size_t)65536 * 4;
  float* a_min = (float*)p;     p += (size_t)65536 * 4;
  unsigned* colmax_u = (unsigned*)p;                        // 256 KiB

  pre_kernel<<<dim3(2048), dim3(256), 0, stream>>>(x, y, xs, ys, x2h, y2h,
                                                   colmax_u, out);
  main_kernel<<<dim3(512), dim3(256), 0, stream>>>(xs, ys, x2h, y2h, a_min,
                                                   colmax_u);
  reduce_kernel<<<dim3(256), dim3(256), 0, stream>>>(colmax_u, y2h, a_min, out);
}